// Round 11
// baseline (1562.918 us; speedup 1.0000x reference)
//
#include <hip/hip_runtime.h>

// ---------------------------------------------------------------------------
// VIN on MI355X (gfx950). B=128, H=W=64, C: 2 -> 150 -> 120 -> 100, q=10, K=36.
// R11: conv2 h1 staging reverted to R9 scalar-fp32 (R10's bf16 MFMA h1 broke
//      accuracy: X/w1 rounded pre-conv1 -> 0.107). NEW: qr_init + 36 VI steps
//      + critic fused into ONE kernel, one block per image:
//        r -> padded LDS, qr bf16 in LDS (80KB), v ping-pong in 2 padded fp32
//        LDS buffers (stride 69, conflict-free), critic dot in-block.
// NHWC bf16 t2 [524288][120], t3 [524288][104]; r fp32 aliased over dead t2.
// ---------------------------------------------------------------------------

#define NHW 524288.0f
#define VSTR 69   // padded v-row stride (odd word count -> 2-way max aliasing)

typedef __attribute__((ext_vector_type(8))) short v8s;
typedef __attribute__((ext_vector_type(4))) float v4f;

static __device__ __forceinline__ float bf2f(unsigned short u) {
  return __uint_as_float(((unsigned int)u) << 16);
}
static __device__ __forceinline__ unsigned short f2bf(float f) {
  unsigned int x = __float_as_uint(f);
  return (unsigned short)((x + 0x7fffu + ((x >> 16) & 1u)) >> 16);  // RNE
}
static __device__ __forceinline__ float wave_sum(float s) {
  #pragma unroll
  for (int off = 32; off > 0; off >>= 1) s += __shfl_down(s, off, 64);
  return s;
}

// -------- weight repack: w[co][ci][3][3] f32 -> [9][128][CIP] bf16 ---------
template <int CO, int CI, int CIP>
__global__ __launch_bounds__(256) void repack_w(
    const float* __restrict__ w, unsigned short* __restrict__ Wp)
{
  int i = blockIdx.x * 256 + threadIdx.x;
  const int total = 9 * 128 * CIP;
  if (i >= total) return;
  int pos = i / (128 * CIP);
  int rem = i - pos * (128 * CIP);
  int co  = rem / CIP;
  int ci  = rem - co * CIP;
  float v = (co < CO && ci < CI) ? w[(co * CI + ci) * 9 + pos] : 0.f;
  Wp[i] = f2bf(v);
}

// ---------------- conv1 (2->150) stats-only, LDS-accumulated ---------------
__global__ __launch_bounds__(256) void conv1_stats(
    const float* __restrict__ X, const float* __restrict__ w1,
    const float* __restrict__ b1, float* __restrict__ S, float* __restrict__ Q)
{
  const int tile = blockIdx.x;             // 128*8
  const int b    = tile >> 3;
  const int y0t  = (tile & 7) * 8;
  const int co0  = blockIdx.y * 15;        // 10 groups of 15
  const int tid  = threadIdx.x;
  const int x    = tid & 63;
  const int ly0  = (tid >> 6) * 2;

  __shared__ float lin[2][10][66];
  __shared__ float ss[15], qq[15];
  if (tid < 15) { ss[tid] = 0.f; qq[tid] = 0.f; }
  for (int idx = tid; idx < 2 * 10 * 66; idx += 256) {
    int cc = idx / 660, rem = idx - cc * 660;
    int rr = rem / 66,  c   = rem - rr * 66;
    int yy = y0t + rr - 1, xx = c - 1;
    lin[cc][rr][c] = (yy >= 0 && yy < 64 && xx >= 0 && xx < 64)
                         ? X[((size_t)(b * 2 + cc) << 12) + (yy << 6) + xx] : 0.f;
  }
  __syncthreads();

  float iv[2][4][3];
  #pragma unroll
  for (int cc = 0; cc < 2; cc++)
    #pragma unroll
    for (int r = 0; r < 4; r++)
      #pragma unroll
      for (int c = 0; c < 3; c++) iv[cc][r][c] = lin[cc][ly0 + r][x + c];

  #pragma unroll
  for (int co = 0; co < 15; co++) {
    const float* w9 = w1 + (size_t)(co0 + co) * 18;
    float a0 = 0.f, a1 = 0.f;
    #pragma unroll
    for (int cc = 0; cc < 2; cc++)
      #pragma unroll
      for (int ky = 0; ky < 3; ky++)
        #pragma unroll
        for (int kx = 0; kx < 3; kx++) {
          float wv = w9[cc * 9 + ky * 3 + kx];
          a0 = fmaf(iv[cc][ky][kx],     wv, a0);
          a1 = fmaf(iv[cc][ky + 1][kx], wv, a1);
        }
    float bz = b1[co0 + co];
    float t0 = a0 + bz, t1 = a1 + bz;
    float s  = wave_sum(t0 + t1);
    float q  = wave_sum(t0 * t0 + t1 * t1);
    if ((tid & 63) == 0) { atomicAdd(&ss[co], s); atomicAdd(&qq[co], q); }
  }
  __syncthreads();
  if (tid < 15) {
    atomicAdd(&S[co0 + tid], ss[tid]);
    atomicAdd(&Q[co0 + tid], qq[tid]);
  }
}

// ---------------- BN finalize ----------------------------------------------
template <int C>
__global__ void bn_finalize(const float* __restrict__ S, const float* __restrict__ Q,
                            const float* __restrict__ g, const float* __restrict__ be,
                            float* __restrict__ A, float* __restrict__ Bs)
{
  int c = threadIdx.x;
  if (c < C) {
    const float invN = 1.f / NHW;
    float m   = S[c] * invN;
    float var = fmaxf(Q[c] * invN - m * m, 0.f);
    float sc  = g[c] * rsqrtf(var + 1e-5f);
    A[c]  = sc;
    Bs[c] = be[c] - m * sc;
  }
}

// ---------------- conv2 MFMA: 256px x 128co, B from global (R9) ------------
__global__ __launch_bounds__(256, 2) void conv2_mfma(
    const float* __restrict__ X,  const float* __restrict__ w1,
    const float* __restrict__ b1f, const float* __restrict__ A1,
    const float* __restrict__ B1, const unsigned short* __restrict__ W2p,
    const float* __restrict__ b2, unsigned short* __restrict__ t2)
{
  const int bx   = blockIdx.x;
  const int b    = bx >> 4;
  const int t16  = bx & 15;
  const int y0   = (t16 >> 2) * 16;
  const int x0   = (t16 & 3) * 16;
  const int tid  = threadIdx.x;
  const int lane = tid & 63;
  const int wid  = __builtin_amdgcn_readfirstlane(tid >> 6);
  const int ln   = lane & 15;
  const int quad = (lane >> 4) * 8;       // ushort offset within 32-ci chunk

  __shared__ __align__(16) float Xs[2][20][20];
  __shared__ float w1s[2700];
  __shared__ float A1s[150], B1s[150], b1s[150], b2s[128];
  __shared__ __align__(16) unsigned short Atile[324 * 34];   // halo px x ci-chunk
  __shared__ __align__(16) unsigned short outs[256 * 68];    // epilogue buffer

  for (int i = tid; i < 2700; i += 256) w1s[i] = w1[i];
  for (int i = tid; i < 150; i += 256) { A1s[i] = A1[i]; B1s[i] = B1[i]; b1s[i] = b1f[i]; }
  if (tid < 128) b2s[tid] = (tid < 120) ? b2[tid] : 0.f;
  for (int i = tid; i < 800; i += 256) {
    int c2 = i / 400, rem = i - c2 * 400;
    int rr = rem / 20, cc = rem - rr * 20;
    int gy = y0 - 2 + rr, gx = x0 - 2 + cc;
    Xs[c2][rr][cc] = (gy >= 0 && gy < 64 && gx >= 0 && gx < 64)
                         ? X[((size_t)(b * 2 + c2) << 12) + (gy << 6) + gx] : 0.f;
  }

  v4f acc[4][8];
  #pragma unroll
  for (int i = 0; i < 4; i++)
    #pragma unroll
    for (int j = 0; j < 8; j++) acc[i][j] = (v4f){0.f, 0.f, 0.f, 0.f};

  for (int chunk = 0; chunk < 5; chunk++) {
    __syncthreads();                      // prior round's Atile reads done
    {
      // stage A chunk: h1 = relu(bn1(conv1(X))) for ci in [32c, 32c+32), fp32
      const int ci_loc = tid & 31;
      const int ci = chunk * 32 + ci_loc;
      const bool live = (ci < 150);
      float wv[18], sc = 0.f, sh = 0.f, bz = 0.f;
      if (live) {
        #pragma unroll
        for (int k = 0; k < 18; k++) wv[k] = w1s[ci * 18 + k];
        sc = A1s[ci]; sh = B1s[ci]; bz = b1s[ci];
      }
      for (int pass = 0; pass < 41; pass++) {
        int p = pass * 8 + (tid >> 5);
        if (p < 324) {
          float v = 0.f;
          if (live) {
            int pr = p / 18, pc = p - pr * 18;
            int hy = y0 - 1 + pr, hx = x0 - 1 + pc;
            if (hy >= 0 && hy < 64 && hx >= 0 && hx < 64) {
              float a = bz;
              #pragma unroll
              for (int c2 = 0; c2 < 2; c2++)
                #pragma unroll
                for (int ky = 0; ky < 3; ky++)
                  #pragma unroll
                  for (int kx = 0; kx < 3; kx++)
                    a = fmaf(Xs[c2][pr + ky][pc + kx], wv[c2 * 9 + ky * 3 + kx], a);
              v = fmaxf(fmaf(a, sc, sh), 0.f);
            }
          }
          Atile[p * 34 + ci_loc] = f2bf(v);
        }
      }
    }
    __syncthreads();

    // register-cache the 18 distinct A fragments for this round
    v8s afr[6][3];
    #pragma unroll
    for (int t = 0; t < 6; t++)
      #pragma unroll
      for (int kx = 0; kx < 3; kx++)
        afr[t][kx] = *(const v8s*)(&Atile[((wid * 4 + t) * 18 + ln + kx) * 34 + quad]);

    #pragma unroll
    for (int pos = 0; pos < 9; pos++) {
      const int ky = pos / 3, kx = pos - ky * 3;
      const unsigned short* bw =
          W2p + (size_t)(pos * 128 + ln) * 160 + chunk * 32 + quad;
      v8s bf[8];
      #pragma unroll
      for (int nj = 0; nj < 8; nj++)
        bf[nj] = *(const v8s*)(bw + (size_t)nj * 16 * 160);
      #pragma unroll
      for (int mi = 0; mi < 4; mi++) {
        #pragma unroll
        for (int nj = 0; nj < 8; nj++)
          acc[mi][nj] = __builtin_amdgcn_mfma_f32_16x16x32_bf16(
              afr[mi + ky][kx], bf[nj], acc[mi][nj], 0, 0, 0);
      }
    }
  }

  // epilogue: two 64-co halves through outs[256][68], NHWC stores
  #pragma unroll
  for (int half = 0; half < 2; half++) {
    __syncthreads();
    #pragma unroll
    for (int mi = 0; mi < 4; mi++)
      #pragma unroll
      for (int njl = 0; njl < 4; njl++) {
        int n = njl * 16 + ln;
        float bz = b2s[half * 64 + n];
        #pragma unroll
        for (int r2 = 0; r2 < 4; r2++) {
          int m = wid * 64 + mi * 16 + (lane >> 4) * 4 + r2;
          outs[m * 68 + n] = f2bf(acc[mi][half * 4 + njl][r2] + bz);
        }
      }
    __syncthreads();
    const int ng = half ? 7 : 8;     // half1 -> co 64..119 (7 ushort8 groups)
    for (int i = tid; i < 256 * ng; i += 256) {
      int p = i / ng, g = i - p * ng;
      int gy = y0 + (p >> 4), gx = x0 + (p & 15);
      size_t gpx = ((size_t)b << 12) + (gy << 6) + gx;
      *(uint4*)(t2 + gpx * 120 + half * 64 + g * 8) =
          *(const uint4*)(&outs[p * 68 + g * 8]);
    }
  }
}

// ---------------- conv3 MFMA: 256px x 128co, B from global -----------------
__global__ __launch_bounds__(256, 2) void conv3_mfma(
    const unsigned short* __restrict__ t2, const float* __restrict__ A2,
    const float* __restrict__ B2, const unsigned short* __restrict__ W3p,
    const float* __restrict__ b3, unsigned short* __restrict__ t3)
{
  const int bx   = blockIdx.x;
  const int b    = bx >> 4;
  const int t16  = bx & 15;
  const int y0   = (t16 >> 2) * 16;
  const int x0   = (t16 & 3) * 16;
  const int tid  = threadIdx.x;
  const int lane = tid & 63;
  const int wid  = __builtin_amdgcn_readfirstlane(tid >> 6);
  const int ln   = lane & 15;
  const int quad = (lane >> 4) * 8;

  __shared__ float A2s[120], B2s[120], b3s[128];
  __shared__ __align__(16) unsigned short Atile[324 * 34];
  __shared__ __align__(16) unsigned short outs[256 * 68];

  for (int i = tid; i < 120; i += 256) { A2s[i] = A2[i]; B2s[i] = B2[i]; }
  if (tid < 128) b3s[tid] = (tid < 100) ? b3[tid] : 0.f;

  v4f acc[4][8];
  #pragma unroll
  for (int i = 0; i < 4; i++)
    #pragma unroll
    for (int j = 0; j < 8; j++) acc[i][j] = (v4f){0.f, 0.f, 0.f, 0.f};

  for (int chunk = 0; chunk < 4; chunk++) {
    __syncthreads();
    {
      // stage A chunk: BN2+ReLU(t2) halo, ci in [32c, 32c+32)
      const int ci0 = chunk * 32;
      const int ngr = (chunk == 3) ? 3 : 4;    // real uint4 groups (ci<120)
      for (int i = tid; i < 1296; i += 256) {  // 324 px x 4 groups
        int p = i >> 2, g = i & 3;
        int pr = p / 18, pc = p - pr * 18;
        int hy = y0 - 1 + pr, hx = x0 - 1 + pc;
        union { uint4 v; unsigned short u[8]; } ov;
        ov.v = (uint4){0, 0, 0, 0};
        if (g < ngr && hy >= 0 && hy < 64 && hx >= 0 && hx < 64) {
          size_t gpx = ((size_t)b << 12) + (hy << 6) + hx;
          union { uint4 v; unsigned short u[8]; } in;
          in.v = *(const uint4*)(t2 + gpx * 120 + ci0 + g * 8);
          #pragma unroll
          for (int j = 0; j < 8; j++) {
            int ci = ci0 + g * 8 + j;
            ov.u[j] = f2bf(fmaxf(fmaf(bf2f(in.u[j]), A2s[ci], B2s[ci]), 0.f));
          }
        }
        *(uint4*)(&Atile[p * 34 + g * 8]) = ov.v;
      }
    }
    __syncthreads();

    v8s afr[6][3];
    #pragma unroll
    for (int t = 0; t < 6; t++)
      #pragma unroll
      for (int kx = 0; kx < 3; kx++)
        afr[t][kx] = *(const v8s*)(&Atile[((wid * 4 + t) * 18 + ln + kx) * 34 + quad]);

    #pragma unroll
    for (int pos = 0; pos < 9; pos++) {
      const int ky = pos / 3, kx = pos - ky * 3;
      const unsigned short* bw =
          W3p + (size_t)(pos * 128 + ln) * 128 + chunk * 32 + quad;
      v8s bf[8];
      #pragma unroll
      for (int nj = 0; nj < 8; nj++)
        bf[nj] = *(const v8s*)(bw + (size_t)nj * 16 * 128);
      #pragma unroll
      for (int mi = 0; mi < 4; mi++) {
        #pragma unroll
        for (int nj = 0; nj < 8; nj++)
          acc[mi][nj] = __builtin_amdgcn_mfma_f32_16x16x32_bf16(
              afr[mi + ky][kx], bf[nj], acc[mi][nj], 0, 0, 0);
      }
    }
  }

  #pragma unroll
  for (int half = 0; half < 2; half++) {
    __syncthreads();
    #pragma unroll
    for (int mi = 0; mi < 4; mi++)
      #pragma unroll
      for (int njl = 0; njl < 4; njl++) {
        int n = njl * 16 + ln;
        float bz = b3s[half * 64 + n];   // 0 for co>=100 (weights also 0)
        #pragma unroll
        for (int r2 = 0; r2 < 4; r2++) {
          int m = wid * 64 + mi * 16 + (lane >> 4) * 4 + r2;
          outs[m * 68 + n] = f2bf(acc[mi][half * 4 + njl][r2] + bz);
        }
      }
    __syncthreads();
    const int ng = half ? 5 : 8;     // half1 -> co 64..103 (100..103 zeros)
    for (int i = tid; i < 256 * ng; i += 256) {
      int p = i / ng, g = i - p * ng;
      int gy = y0 + (p >> 4), gx = x0 + (p & 15);
      size_t gpx = ((size_t)b << 12) + (gy << 6) + gx;
      *(uint4*)(t3 + gpx * 104 + half * 64 + g * 8) =
          *(const uint4*)(&outs[p * 68 + g * 8]);
    }
  }
}

// ---------------- per-channel sums over NHWC bf16 tensor -------------------
template <int ST, int NG, int C>
__global__ __launch_bounds__(256) void nhwc_stats(
    const unsigned short* __restrict__ t, float* __restrict__ S, float* __restrict__ Q)
{
  const int tid = threadIdx.x;
  const int g   = tid & 15;
  const int pl  = tid >> 4;
  const bool valid = (g < NG);
  const int px0 = blockIdx.x * 512;

  __shared__ float ss[128], qq[128];
  for (int i = tid; i < 128; i += 256) { ss[i] = 0.f; qq[i] = 0.f; }
  __syncthreads();

  float s8[8], q8[8];
  #pragma unroll
  for (int j = 0; j < 8; j++) { s8[j] = 0.f; q8[j] = 0.f; }

  if (valid) {
    for (int it = 0; it < 32; it++) {
      size_t px = px0 + it * 16 + pl;
      union { uint4 v; unsigned short u[8]; } in;
      in.v = *(const uint4*)(t + px * ST + g * 8);
      #pragma unroll
      for (int j = 0; j < 8; j++) {
        float v = bf2f(in.u[j]);
        s8[j] += v;
        q8[j] += v * v;
      }
    }
    #pragma unroll
    for (int j = 0; j < 8; j++) {
      atomicAdd(&ss[g * 8 + j], s8[j]);
      atomicAdd(&qq[g * 8 + j], q8[j]);
    }
  }
  __syncthreads();
  if (tid < C) {
    atomicAdd(&S[tid], ss[tid]);
    atomicAdd(&Q[tid], qq[tid]);
  }
}

// ---------------- BN3+ReLU+1x1 reward reduce over NHWC t3 ------------------
__global__ __launch_bounds__(256) void bn3_reduce_r(
    const unsigned short* __restrict__ t3, const float* __restrict__ A3,
    const float* __restrict__ B3, const float* __restrict__ rw,
    float* __restrict__ r)
{
  __shared__ float A3s[104], B3s[104], rws[104];
  const int tid = threadIdx.x;
  for (int i = tid; i < 104; i += 256) {
    bool v = (i < 100);
    A3s[i] = v ? A3[i] : 0.f;
    B3s[i] = v ? B3[i] : 0.f;
    rws[i] = v ? rw[i] : 0.f;
  }
  __syncthreads();

  size_t px = (size_t)blockIdx.x * 256 + tid;
  const unsigned short* p = t3 + px * 104;
  float a = 0.f;
  #pragma unroll
  for (int gq = 0; gq < 13; gq++) {
    union { uint4 v; unsigned short u[8]; } in;
    in.v = *(const uint4*)(p + gq * 8);
    #pragma unroll
    for (int j = 0; j < 8; j++) {
      int ci = gq * 8 + j;
      a = fmaf(fmaxf(fmaf(bf2f(in.u[j]), A3s[ci], B3s[ci]), 0.f), rws[ci], a);
    }
  }
  r[px] = a;
}

// ---------------- fused VI: qr_init + 36 steps + critic, 1 block/image -----
// LDS: qrs [10][4096] bf16 (80KB) + vbuf[2][68][69] fp32 (37.5KB).
// v buffers zero-padded (halo 2) -> no bounds checks in the 5x5 conv.
__global__ __launch_bounds__(512, 1) void vi_fused(
    const float* __restrict__ r,   const float* __restrict__ qw,
    const float* __restrict__ ww,  const float* __restrict__ cvw,
    const float* __restrict__ cvb, float* __restrict__ out)
{
  const int b   = blockIdx.x;
  const int tid = threadIdx.x;

  __shared__ unsigned short qrs[10 * 4096];
  __shared__ float vbuf[2][68 * VSTR];
  __shared__ float part[8];

  // zero both v buffers (pads stay 0 forever; interiors overwritten below)
  for (int i = tid; i < 2 * 68 * VSTR; i += 512) ((float*)vbuf)[i] = 0.f;
  __syncthreads();

  // r -> vbuf[0] interior
  const float* rb = r + ((size_t)b << 12);
  #pragma unroll
  for (int j = 0; j < 8; j++) {
    int px = tid + 512 * j;
    int y = px >> 6, x = px & 63;
    vbuf[0][(y + 2) * VSTR + (x + 2)] = rb[px];
  }
  __syncthreads();

  // qrs = bf16(conv5x5(r, qw)); vbuf[1] = v0 = max_a qr
  #pragma unroll
  for (int j = 0; j < 8; j++) {
    int px = tid + 512 * j;
    int y = px >> 6, x = px & 63;
    float tap[25];
    #pragma unroll
    for (int t = 0; t < 25; t++)
      tap[t] = vbuf[0][(y + t / 5) * VSTR + x + (t % 5)];
    float vmax = -1e30f;
    #pragma unroll
    for (int a = 0; a < 10; a++) {
      float q = 0.f;
      #pragma unroll
      for (int t = 0; t < 25; t++) q = fmaf(tap[t], qw[a * 25 + t], q);
      qrs[a * 4096 + px] = f2bf(q);
      vmax = fmaxf(vmax, q);
    }
    vbuf[1][(y + 2) * VSTR + (x + 2)] = vmax;
  }
  __syncthreads();

  // 36 VI steps, ping-pong vbuf[1] <-> vbuf[0]; final lands in vbuf[1]
  for (int s = 0; s < 36; s++) {
    const float* src = vbuf[1 - (s & 1)];
    float* dst       = vbuf[s & 1];
    #pragma unroll
    for (int j = 0; j < 8; j++) {
      int px = tid + 512 * j;
      int y = px >> 6, x = px & 63;
      float tap[25];
      #pragma unroll
      for (int t = 0; t < 25; t++)
        tap[t] = src[(y + t / 5) * VSTR + x + (t % 5)];
      float vmax = -1e30f;
      #pragma unroll
      for (int a = 0; a < 10; a++) {
        float q = bf2f(qrs[a * 4096 + px]);
        #pragma unroll
        for (int t = 0; t < 25; t++) q = fmaf(tap[t], ww[a * 25 + t], q);
        vmax = fmaxf(vmax, q);
      }
      dst[(y + 2) * VSTR + (x + 2)] = vmax;
    }
    __syncthreads();
  }

  // critic: out[b] = dot(v, cv_w) + cv_b   (final v in vbuf[1])
  float ssum = 0.f;
  #pragma unroll
  for (int j = 0; j < 8; j++) {
    int px = tid + 512 * j;
    int y = px >> 6, x = px & 63;
    ssum = fmaf(vbuf[1][(y + 2) * VSTR + (x + 2)], cvw[px], ssum);
  }
  ssum = wave_sum(ssum);
  if ((tid & 63) == 0) part[tid >> 6] = ssum;
  __syncthreads();
  if (tid == 0) {
    float t = 0.f;
    #pragma unroll
    for (int i2 = 0; i2 < 8; i2++) t += part[i2];
    out[b] = t + cvb[0];
  }
}

// ---------------- action MLP ----------------------------------------------
__global__ __launch_bounds__(128) void action_k(
    const float* __restrict__ obs, const float* __restrict__ fc1w,
    const float* __restrict__ fc1b, const float* __restrict__ fc2w,
    const float* __restrict__ fc2b, float* __restrict__ out)
{
  const int b = blockIdx.x;
  const int j = threadIdx.x;
  __shared__ float ob[24];
  __shared__ float h[100];
  if (j < 24) ob[j] = obs[b * 24 + j];
  __syncthreads();
  if (j < 100) {
    float s = fc1b[j];
    #pragma unroll
    for (int k = 0; k < 24; k++) s = fmaf(ob[k], fc1w[j * 24 + k], s);
    h[j] = fmaxf(s, 0.f);
  }
  __syncthreads();
  if (j < 10) {
    float s = fc2b[j];
    for (int k = 0; k < 100; k++) s = fmaf(h[k], fc2w[j * 100 + k], s);
    out[128 + b * 10 + j] = fmaxf(s, 0.f);
  }
}

// ---------------------------------------------------------------------------
extern "C" void kernel_launch(void* const* d_in, const int* in_sizes, int n_in,
                              void* d_out, int out_size, void* d_ws,
                              size_t ws_size, hipStream_t stream)
{
  const float* X     = (const float*)d_in[0];
  const float* obs   = (const float*)d_in[1];
  const float* h1_w  = (const float*)d_in[2];
  const float* h1_b  = (const float*)d_in[3];
  const float* g1    = (const float*)d_in[4];
  const float* b1    = (const float*)d_in[5];
  const float* h2_w  = (const float*)d_in[6];
  const float* h2_b  = (const float*)d_in[7];
  const float* g2    = (const float*)d_in[8];
  const float* b2    = (const float*)d_in[9];
  const float* h3_w  = (const float*)d_in[10];
  const float* h3_b  = (const float*)d_in[11];
  const float* g3    = (const float*)d_in[12];
  const float* b3    = (const float*)d_in[13];
  const float* r_w   = (const float*)d_in[14];
  const float* q_w   = (const float*)d_in[15];
  const float* w_vi  = (const float*)d_in[16];
  const float* fc1_w = (const float*)d_in[17];
  const float* fc1_b = (const float*)d_in[18];
  const float* fc2_w = (const float*)d_in[19];
  const float* fc2_b = (const float*)d_in[20];
  const float* cv_w  = (const float*)d_in[21];
  const float* cv_b  = (const float*)d_in[22];
  // K (d_in[23]) fixed to 36 by setup; loop count is compile-time.

  char* ws = (char*)d_ws;
  unsigned short* t2  = (unsigned short*)ws;                       // 125,829,120 B
  unsigned short* t3  = (unsigned short*)(ws + 125829120ull);      // 109,051,904 B
  unsigned short* W2p = (unsigned short*)(ws + 234881024ull);      //     368,640 B
  unsigned short* W3p = (unsigned short*)(ws + 235249664ull);      //     294,912 B
  float*          ST  = (float*)         (ws + 235544576ull);      //       5,920 B
  float* S1 = ST +    0; float* Q1 = ST +  150; float* A1 = ST +  300; float* B1 = ST +  450;
  float* S2 = ST +  600; float* Q2 = ST +  720; float* A2 = ST +  840; float* B2 = ST +  960;
  float* S3 = ST + 1080; float* Q3 = ST + 1180; float* A3 = ST + 1280; float* B3 = ST + 1380;
  // r (fp32, 2MB) aliased over dead t2 region
  float* r = (float*)ws;

  hipMemsetAsync(ST, 0, 1480 * sizeof(float), stream);

  repack_w<120, 150, 160><<<720, 256, 0, stream>>>(h2_w, W2p);
  repack_w<100, 120, 128><<<576, 256, 0, stream>>>(h3_w, W3p);

  conv1_stats<<<dim3(1024, 10), 256, 0, stream>>>(X, h1_w, h1_b, S1, Q1);
  bn_finalize<150><<<1, 256, 0, stream>>>(S1, Q1, g1, b1, A1, B1);

  conv2_mfma<<<2048, 256, 0, stream>>>(X, h1_w, h1_b, A1, B1, W2p, h2_b, t2);
  nhwc_stats<120, 15, 120><<<1024, 256, 0, stream>>>(t2, S2, Q2);
  bn_finalize<120><<<1, 256, 0, stream>>>(S2, Q2, g2, b2, A2, B2);

  conv3_mfma<<<2048, 256, 0, stream>>>(t2, A2, B2, W3p, h3_b, t3);
  nhwc_stats<104, 13, 100><<<1024, 256, 0, stream>>>(t3, S3, Q3);
  bn_finalize<100><<<1, 256, 0, stream>>>(S3, Q3, g3, b3, A3, B3);

  bn3_reduce_r<<<2048, 256, 0, stream>>>(t3, A3, B3, r_w, r);

  float* out = (float*)d_out;
  vi_fused<<<128, 512, 0, stream>>>(r, q_w, w_vi, cv_w, cv_b, out);
  action_k<<<128, 128, 0, stream>>>(obs, fc1_w, fc1_b, fc2_w, fc2_b, out);
}

// Round 12
// 1291.887 us; speedup vs baseline: 1.2098x; 1.2098x over previous
//
#include <hip/hip_runtime.h>

// ---------------------------------------------------------------------------
// VIN on MI355X (gfx950). B=128, H=W=64, C: 2 -> 150 -> 120 -> 100, q=10, K=36.
// R12: R9 structure (separate full-grid VI kernels — R11's 1-block/image
//      fusion left half the CUs idle). New vs R9:
//   - BN2/BN3 stats fused into conv2/conv3 epilogues (from the outs LDS
//     buffer = exactly the stored bf16 values); nhwc_stats kernels dropped.
//   - qr stored bf16 (R11-validated): halves VI-phase qr traffic.
// NHWC bf16 t2 [524288][120], t3 [524288][104]; VI bufs aliased over dead t2.
// ---------------------------------------------------------------------------

#define NHW 524288.0f

typedef __attribute__((ext_vector_type(8))) short v8s;
typedef __attribute__((ext_vector_type(4))) float v4f;

static __device__ __forceinline__ float bf2f(unsigned short u) {
  return __uint_as_float(((unsigned int)u) << 16);
}
static __device__ __forceinline__ unsigned short f2bf(float f) {
  unsigned int x = __float_as_uint(f);
  return (unsigned short)((x + 0x7fffu + ((x >> 16) & 1u)) >> 16);  // RNE
}
static __device__ __forceinline__ float wave_sum(float s) {
  #pragma unroll
  for (int off = 32; off > 0; off >>= 1) s += __shfl_down(s, off, 64);
  return s;
}

// -------- weight repack: w[co][ci][3][3] f32 -> [9][128][CIP] bf16 ---------
template <int CO, int CI, int CIP>
__global__ __launch_bounds__(256) void repack_w(
    const float* __restrict__ w, unsigned short* __restrict__ Wp)
{
  int i = blockIdx.x * 256 + threadIdx.x;
  const int total = 9 * 128 * CIP;
  if (i >= total) return;
  int pos = i / (128 * CIP);
  int rem = i - pos * (128 * CIP);
  int co  = rem / CIP;
  int ci  = rem - co * CIP;
  float v = (co < CO && ci < CI) ? w[(co * CI + ci) * 9 + pos] : 0.f;
  Wp[i] = f2bf(v);
}

// ---------------- conv1 (2->150) stats-only, LDS-accumulated ---------------
__global__ __launch_bounds__(256) void conv1_stats(
    const float* __restrict__ X, const float* __restrict__ w1,
    const float* __restrict__ b1, float* __restrict__ S, float* __restrict__ Q)
{
  const int tile = blockIdx.x;             // 128*8
  const int b    = tile >> 3;
  const int y0t  = (tile & 7) * 8;
  const int co0  = blockIdx.y * 15;        // 10 groups of 15
  const int tid  = threadIdx.x;
  const int x    = tid & 63;
  const int ly0  = (tid >> 6) * 2;

  __shared__ float lin[2][10][66];
  __shared__ float ss[15], qq[15];
  if (tid < 15) { ss[tid] = 0.f; qq[tid] = 0.f; }
  for (int idx = tid; idx < 2 * 10 * 66; idx += 256) {
    int cc = idx / 660, rem = idx - cc * 660;
    int rr = rem / 66,  c   = rem - rr * 66;
    int yy = y0t + rr - 1, xx = c - 1;
    lin[cc][rr][c] = (yy >= 0 && yy < 64 && xx >= 0 && xx < 64)
                         ? X[((size_t)(b * 2 + cc) << 12) + (yy << 6) + xx] : 0.f;
  }
  __syncthreads();

  float iv[2][4][3];
  #pragma unroll
  for (int cc = 0; cc < 2; cc++)
    #pragma unroll
    for (int r = 0; r < 4; r++)
      #pragma unroll
      for (int c = 0; c < 3; c++) iv[cc][r][c] = lin[cc][ly0 + r][x + c];

  #pragma unroll
  for (int co = 0; co < 15; co++) {
    const float* w9 = w1 + (size_t)(co0 + co) * 18;
    float a0 = 0.f, a1 = 0.f;
    #pragma unroll
    for (int cc = 0; cc < 2; cc++)
      #pragma unroll
      for (int ky = 0; ky < 3; ky++)
        #pragma unroll
        for (int kx = 0; kx < 3; kx++) {
          float wv = w9[cc * 9 + ky * 3 + kx];
          a0 = fmaf(iv[cc][ky][kx],     wv, a0);
          a1 = fmaf(iv[cc][ky + 1][kx], wv, a1);
        }
    float bz = b1[co0 + co];
    float t0 = a0 + bz, t1 = a1 + bz;
    float s  = wave_sum(t0 + t1);
    float q  = wave_sum(t0 * t0 + t1 * t1);
    if ((tid & 63) == 0) { atomicAdd(&ss[co], s); atomicAdd(&qq[co], q); }
  }
  __syncthreads();
  if (tid < 15) {
    atomicAdd(&S[co0 + tid], ss[tid]);
    atomicAdd(&Q[co0 + tid], qq[tid]);
  }
}

// ---------------- BN finalize ----------------------------------------------
template <int C>
__global__ void bn_finalize(const float* __restrict__ S, const float* __restrict__ Q,
                            const float* __restrict__ g, const float* __restrict__ be,
                            float* __restrict__ A, float* __restrict__ Bs)
{
  int c = threadIdx.x;
  if (c < C) {
    const float invN = 1.f / NHW;
    float m   = S[c] * invN;
    float var = fmaxf(Q[c] * invN - m * m, 0.f);
    float sc  = g[c] * rsqrtf(var + 1e-5f);
    A[c]  = sc;
    Bs[c] = be[c] - m * sc;
  }
}

// ---------------- conv2 MFMA: 256px x 128co, B from global, stats fused ----
__global__ __launch_bounds__(256, 2) void conv2_mfma(
    const float* __restrict__ X,  const float* __restrict__ w1,
    const float* __restrict__ b1f, const float* __restrict__ A1,
    const float* __restrict__ B1, const unsigned short* __restrict__ W2p,
    const float* __restrict__ b2, unsigned short* __restrict__ t2,
    float* __restrict__ S2, float* __restrict__ Q2)
{
  const int bx   = blockIdx.x;
  const int b    = bx >> 4;
  const int t16  = bx & 15;
  const int y0   = (t16 >> 2) * 16;
  const int x0   = (t16 & 3) * 16;
  const int tid  = threadIdx.x;
  const int lane = tid & 63;
  const int wid  = __builtin_amdgcn_readfirstlane(tid >> 6);
  const int ln   = lane & 15;
  const int quad = (lane >> 4) * 8;       // ushort offset within 32-ci chunk

  __shared__ __align__(16) float Xs[2][20][20];
  __shared__ float w1s[2700];
  __shared__ float A1s[150], B1s[150], b1s[150], b2s[128];
  __shared__ float ssB[128], qqB[128];
  __shared__ __align__(16) unsigned short Atile[324 * 34];   // halo px x ci-chunk
  __shared__ __align__(16) unsigned short outs[256 * 68];    // epilogue buffer

  for (int i = tid; i < 2700; i += 256) w1s[i] = w1[i];
  for (int i = tid; i < 150; i += 256) { A1s[i] = A1[i]; B1s[i] = B1[i]; b1s[i] = b1f[i]; }
  if (tid < 128) { b2s[tid] = (tid < 120) ? b2[tid] : 0.f; ssB[tid] = 0.f; qqB[tid] = 0.f; }
  for (int i = tid; i < 800; i += 256) {
    int c2 = i / 400, rem = i - c2 * 400;
    int rr = rem / 20, cc = rem - rr * 20;
    int gy = y0 - 2 + rr, gx = x0 - 2 + cc;
    Xs[c2][rr][cc] = (gy >= 0 && gy < 64 && gx >= 0 && gx < 64)
                         ? X[((size_t)(b * 2 + c2) << 12) + (gy << 6) + gx] : 0.f;
  }

  v4f acc[4][8];
  #pragma unroll
  for (int i = 0; i < 4; i++)
    #pragma unroll
    for (int j = 0; j < 8; j++) acc[i][j] = (v4f){0.f, 0.f, 0.f, 0.f};

  for (int chunk = 0; chunk < 5; chunk++) {
    __syncthreads();                      // prior round's Atile reads done
    {
      // stage A chunk: h1 = relu(bn1(conv1(X))) for ci in [32c, 32c+32), fp32
      const int ci_loc = tid & 31;
      const int ci = chunk * 32 + ci_loc;
      const bool live = (ci < 150);
      float wv[18], sc = 0.f, sh = 0.f, bz = 0.f;
      if (live) {
        #pragma unroll
        for (int k = 0; k < 18; k++) wv[k] = w1s[ci * 18 + k];
        sc = A1s[ci]; sh = B1s[ci]; bz = b1s[ci];
      }
      for (int pass = 0; pass < 41; pass++) {
        int p = pass * 8 + (tid >> 5);
        if (p < 324) {
          float v = 0.f;
          if (live) {
            int pr = p / 18, pc = p - pr * 18;
            int hy = y0 - 1 + pr, hx = x0 - 1 + pc;
            if (hy >= 0 && hy < 64 && hx >= 0 && hx < 64) {
              float a = bz;
              #pragma unroll
              for (int c2 = 0; c2 < 2; c2++)
                #pragma unroll
                for (int ky = 0; ky < 3; ky++)
                  #pragma unroll
                  for (int kx = 0; kx < 3; kx++)
                    a = fmaf(Xs[c2][pr + ky][pc + kx], wv[c2 * 9 + ky * 3 + kx], a);
              v = fmaxf(fmaf(a, sc, sh), 0.f);
            }
          }
          Atile[p * 34 + ci_loc] = f2bf(v);
        }
      }
    }
    __syncthreads();

    // register-cache the 18 distinct A fragments for this round
    v8s afr[6][3];
    #pragma unroll
    for (int t = 0; t < 6; t++)
      #pragma unroll
      for (int kx = 0; kx < 3; kx++)
        afr[t][kx] = *(const v8s*)(&Atile[((wid * 4 + t) * 18 + ln + kx) * 34 + quad]);

    #pragma unroll
    for (int pos = 0; pos < 9; pos++) {
      const int ky = pos / 3, kx = pos - ky * 3;
      const unsigned short* bw =
          W2p + (size_t)(pos * 128 + ln) * 160 + chunk * 32 + quad;
      v8s bf[8];
      #pragma unroll
      for (int nj = 0; nj < 8; nj++)
        bf[nj] = *(const v8s*)(bw + (size_t)nj * 16 * 160);
      #pragma unroll
      for (int mi = 0; mi < 4; mi++) {
        #pragma unroll
        for (int nj = 0; nj < 8; nj++)
          acc[mi][nj] = __builtin_amdgcn_mfma_f32_16x16x32_bf16(
              afr[mi + ky][kx], bf[nj], acc[mi][nj], 0, 0, 0);
      }
    }
  }

  // epilogue: two 64-co halves through outs[256][68]; NHWC stores + stats
  #pragma unroll
  for (int half = 0; half < 2; half++) {
    __syncthreads();
    #pragma unroll
    for (int mi = 0; mi < 4; mi++)
      #pragma unroll
      for (int njl = 0; njl < 4; njl++) {
        int n = njl * 16 + ln;
        float bz = b2s[half * 64 + n];
        #pragma unroll
        for (int r2 = 0; r2 < 4; r2++) {
          int m = wid * 64 + mi * 16 + (lane >> 4) * 4 + r2;
          outs[m * 68 + n] = f2bf(acc[mi][half * 4 + njl][r2] + bz);
        }
      }
    __syncthreads();
    const int ng = half ? 7 : 8;     // half1 -> co 64..119 (7 ushort8 groups)
    for (int i = tid; i < 256 * ng; i += 256) {
      int p = i / ng, g = i - p * ng;
      int gy = y0 + (p >> 4), gx = x0 + (p & 15);
      size_t gpx = ((size_t)b << 12) + (gy << 6) + gx;
      *(uint4*)(t2 + gpx * 120 + half * 64 + g * 8) =
          *(const uint4*)(&outs[p * 68 + g * 8]);
    }
    // fused BN2 stats from the stored (bf16) values
    {
      float ls = 0.f, lq = 0.f;
      const int c = tid & 63, pr0 = (tid >> 6) * 64;
      for (int p = 0; p < 64; p++) {
        float v = bf2f(outs[(pr0 + p) * 68 + c]);
        ls += v; lq += v * v;
      }
      atomicAdd(&ssB[half * 64 + c], ls);
      atomicAdd(&qqB[half * 64 + c], lq);
    }
  }
  __syncthreads();
  if (tid < 120) {
    atomicAdd(&S2[tid], ssB[tid]);
    atomicAdd(&Q2[tid], qqB[tid]);
  }
}

// ---------------- conv3 MFMA: 256px x 128co, B from global, stats fused ----
__global__ __launch_bounds__(256, 2) void conv3_mfma(
    const unsigned short* __restrict__ t2, const float* __restrict__ A2,
    const float* __restrict__ B2, const unsigned short* __restrict__ W3p,
    const float* __restrict__ b3, unsigned short* __restrict__ t3,
    float* __restrict__ S3, float* __restrict__ Q3)
{
  const int bx   = blockIdx.x;
  const int b    = bx >> 4;
  const int t16  = bx & 15;
  const int y0   = (t16 >> 2) * 16;
  const int x0   = (t16 & 3) * 16;
  const int tid  = threadIdx.x;
  const int lane = tid & 63;
  const int wid  = __builtin_amdgcn_readfirstlane(tid >> 6);
  const int ln   = lane & 15;
  const int quad = (lane >> 4) * 8;

  __shared__ float A2s[120], B2s[120], b3s[128];
  __shared__ float ssB[128], qqB[128];
  __shared__ __align__(16) unsigned short Atile[324 * 34];
  __shared__ __align__(16) unsigned short outs[256 * 68];

  for (int i = tid; i < 120; i += 256) { A2s[i] = A2[i]; B2s[i] = B2[i]; }
  if (tid < 128) { b3s[tid] = (tid < 100) ? b3[tid] : 0.f; ssB[tid] = 0.f; qqB[tid] = 0.f; }

  v4f acc[4][8];
  #pragma unroll
  for (int i = 0; i < 4; i++)
    #pragma unroll
    for (int j = 0; j < 8; j++) acc[i][j] = (v4f){0.f, 0.f, 0.f, 0.f};

  for (int chunk = 0; chunk < 4; chunk++) {
    __syncthreads();
    {
      // stage A chunk: BN2+ReLU(t2) halo, ci in [32c, 32c+32)
      const int ci0 = chunk * 32;
      const int ngr = (chunk == 3) ? 3 : 4;    // real uint4 groups (ci<120)
      for (int i = tid; i < 1296; i += 256) {  // 324 px x 4 groups
        int p = i >> 2, g = i & 3;
        int pr = p / 18, pc = p - pr * 18;
        int hy = y0 - 1 + pr, hx = x0 - 1 + pc;
        union { uint4 v; unsigned short u[8]; } ov;
        ov.v = (uint4){0, 0, 0, 0};
        if (g < ngr && hy >= 0 && hy < 64 && hx >= 0 && hx < 64) {
          size_t gpx = ((size_t)b << 12) + (hy << 6) + hx;
          union { uint4 v; unsigned short u[8]; } in;
          in.v = *(const uint4*)(t2 + gpx * 120 + ci0 + g * 8);
          #pragma unroll
          for (int j = 0; j < 8; j++) {
            int ci = ci0 + g * 8 + j;
            ov.u[j] = f2bf(fmaxf(fmaf(bf2f(in.u[j]), A2s[ci], B2s[ci]), 0.f));
          }
        }
        *(uint4*)(&Atile[p * 34 + g * 8]) = ov.v;
      }
    }
    __syncthreads();

    v8s afr[6][3];
    #pragma unroll
    for (int t = 0; t < 6; t++)
      #pragma unroll
      for (int kx = 0; kx < 3; kx++)
        afr[t][kx] = *(const v8s*)(&Atile[((wid * 4 + t) * 18 + ln + kx) * 34 + quad]);

    #pragma unroll
    for (int pos = 0; pos < 9; pos++) {
      const int ky = pos / 3, kx = pos - ky * 3;
      const unsigned short* bw =
          W3p + (size_t)(pos * 128 + ln) * 128 + chunk * 32 + quad;
      v8s bf[8];
      #pragma unroll
      for (int nj = 0; nj < 8; nj++)
        bf[nj] = *(const v8s*)(bw + (size_t)nj * 16 * 128);
      #pragma unroll
      for (int mi = 0; mi < 4; mi++) {
        #pragma unroll
        for (int nj = 0; nj < 8; nj++)
          acc[mi][nj] = __builtin_amdgcn_mfma_f32_16x16x32_bf16(
              afr[mi + ky][kx], bf[nj], acc[mi][nj], 0, 0, 0);
      }
    }
  }

  #pragma unroll
  for (int half = 0; half < 2; half++) {
    __syncthreads();
    #pragma unroll
    for (int mi = 0; mi < 4; mi++)
      #pragma unroll
      for (int njl = 0; njl < 4; njl++) {
        int n = njl * 16 + ln;
        float bz = b3s[half * 64 + n];   // 0 for co>=100 (weights also 0)
        #pragma unroll
        for (int r2 = 0; r2 < 4; r2++) {
          int m = wid * 64 + mi * 16 + (lane >> 4) * 4 + r2;
          outs[m * 68 + n] = f2bf(acc[mi][half * 4 + njl][r2] + bz);
        }
      }
    __syncthreads();
    const int ng = half ? 5 : 8;     // half1 -> co 64..103 (100..103 zeros)
    for (int i = tid; i < 256 * ng; i += 256) {
      int p = i / ng, g = i - p * ng;
      int gy = y0 + (p >> 4), gx = x0 + (p & 15);
      size_t gpx = ((size_t)b << 12) + (gy << 6) + gx;
      *(uint4*)(t3 + gpx * 104 + half * 64 + g * 8) =
          *(const uint4*)(&outs[p * 68 + g * 8]);
    }
    {
      float ls = 0.f, lq = 0.f;
      const int c = tid & 63, pr0 = (tid >> 6) * 64;
      for (int p = 0; p < 64; p++) {
        float v = bf2f(outs[(pr0 + p) * 68 + c]);
        ls += v; lq += v * v;
      }
      atomicAdd(&ssB[half * 64 + c], ls);
      atomicAdd(&qqB[half * 64 + c], lq);
    }
  }
  __syncthreads();
  if (tid < 100) {
    atomicAdd(&S3[tid], ssB[tid]);
    atomicAdd(&Q3[tid], qqB[tid]);
  }
}

// ---------------- BN3+ReLU+1x1 reward reduce over NHWC t3 ------------------
__global__ __launch_bounds__(256) void bn3_reduce_r(
    const unsigned short* __restrict__ t3, const float* __restrict__ A3,
    const float* __restrict__ B3, const float* __restrict__ rw,
    float* __restrict__ r)
{
  __shared__ float A3s[104], B3s[104], rws[104];
  const int tid = threadIdx.x;
  for (int i = tid; i < 104; i += 256) {
    bool v = (i < 100);
    A3s[i] = v ? A3[i] : 0.f;
    B3s[i] = v ? B3[i] : 0.f;
    rws[i] = v ? rw[i] : 0.f;
  }
  __syncthreads();

  size_t px = (size_t)blockIdx.x * 256 + tid;
  const unsigned short* p = t3 + px * 104;
  float a = 0.f;
  #pragma unroll
  for (int gq = 0; gq < 13; gq++) {
    union { uint4 v; unsigned short u[8]; } in;
    in.v = *(const uint4*)(p + gq * 8);
    #pragma unroll
    for (int j = 0; j < 8; j++) {
      int ci = gq * 8 + j;
      a = fmaf(fmaxf(fmaf(bf2f(in.u[j]), A3s[ci], B3s[ci]), 0.f), rws[ci], a);
    }
  }
  r[px] = a;
}

// ---------------- qr = conv5x5(r, q_w) (bf16); v0 = max_a qr ---------------
__global__ __launch_bounds__(256) void qr_init(
    const float* __restrict__ r, const float* __restrict__ qw,
    unsigned short* __restrict__ qr, float* __restrict__ v0)
{
  const int tile = blockIdx.x;          // 128*16
  const int b    = tile >> 4;
  const int y0t  = (tile & 15) * 4;
  const int tid  = threadIdx.x;
  const int x    = tid & 63;
  const int ly   = tid >> 6;

  __shared__ float lv[8][68];
  for (int idx = tid; idx < 8 * 68; idx += 256) {
    int rr = idx / 68, c = idx - rr * 68;
    int yy = y0t + rr - 2, xx = c - 2;
    lv[rr][c] = (yy >= 0 && yy < 64 && xx >= 0 && xx < 64)
                    ? r[((size_t)b << 12) + (yy << 6) + xx] : 0.f;
  }
  __syncthreads();

  float iv[5][5];
  #pragma unroll
  for (int ky = 0; ky < 5; ky++)
    #pragma unroll
    for (int kx = 0; kx < 5; kx++) iv[ky][kx] = lv[ly + ky][x + kx];

  const int y = y0t + ly;
  float vmax = -1e30f;
  #pragma unroll
  for (int a = 0; a < 10; a++) {
    float q = 0.f;
    #pragma unroll
    for (int ky = 0; ky < 5; ky++)
      #pragma unroll
      for (int kx = 0; kx < 5; kx++)
        q = fmaf(iv[ky][kx], qw[a * 25 + ky * 5 + kx], q);
    qr[((size_t)(b * 10 + a) << 12) + (y << 6) + x] = f2bf(q);
    vmax = fmaxf(vmax, q);
  }
  v0[((size_t)b << 12) + (y << 6) + x] = vmax;
}

// ---------------- VI step: v' = max_a (qr + conv5x5(v, w)) -----------------
__global__ __launch_bounds__(256) void vi_step(
    const float* __restrict__ vin, const unsigned short* __restrict__ qr,
    const float* __restrict__ ww, float* __restrict__ vout)
{
  const int tile = blockIdx.x;
  const int b    = tile >> 4;
  const int y0t  = (tile & 15) * 4;
  const int tid  = threadIdx.x;
  const int x    = tid & 63;
  const int ly   = tid >> 6;

  __shared__ float lv[8][68];
  for (int idx = tid; idx < 8 * 68; idx += 256) {
    int rr = idx / 68, c = idx - rr * 68;
    int yy = y0t + rr - 2, xx = c - 2;
    lv[rr][c] = (yy >= 0 && yy < 64 && xx >= 0 && xx < 64)
                    ? vin[((size_t)b << 12) + (yy << 6) + xx] : 0.f;
  }
  __syncthreads();

  float iv[5][5];
  #pragma unroll
  for (int ky = 0; ky < 5; ky++)
    #pragma unroll
    for (int kx = 0; kx < 5; kx++) iv[ky][kx] = lv[ly + ky][x + kx];

  const int y = y0t + ly;
  float vmax = -1e30f;
  #pragma unroll
  for (int a = 0; a < 10; a++) {
    float q = bf2f(qr[((size_t)(b * 10 + a) << 12) + (y << 6) + x]);
    #pragma unroll
    for (int ky = 0; ky < 5; ky++)
      #pragma unroll
      for (int kx = 0; kx < 5; kx++)
        q = fmaf(iv[ky][kx], ww[a * 25 + ky * 5 + kx], q);
    vmax = fmaxf(vmax, q);
  }
  vout[((size_t)b << 12) + (y << 6) + x] = vmax;
}

// ---------------- critic ---------------------------------------------------
__global__ __launch_bounds__(256) void critic_k(
    const float* __restrict__ v, const float* __restrict__ cvw,
    const float* __restrict__ cvb, float* __restrict__ out)
{
  const int b = blockIdx.x;
  const int tid = threadIdx.x;
  const float4* pv = (const float4*)(v + ((size_t)b << 12));
  const float4* pw = (const float4*)cvw;
  float s = 0.f;
  #pragma unroll
  for (int i = 0; i < 4; i++) {
    float4 a = pv[tid + 256 * i];
    float4 w = pw[tid + 256 * i];
    s += a.x * w.x + a.y * w.y + a.z * w.z + a.w * w.w;
  }
  s = wave_sum(s);
  __shared__ float ls[4];
  const int w = tid >> 6;
  if ((tid & 63) == 0) ls[w] = s;
  __syncthreads();
  if (tid == 0) out[b] = ls[0] + ls[1] + ls[2] + ls[3] + cvb[0];
}

// ---------------- action MLP ----------------------------------------------
__global__ __launch_bounds__(128) void action_k(
    const float* __restrict__ obs, const float* __restrict__ fc1w,
    const float* __restrict__ fc1b, const float* __restrict__ fc2w,
    const float* __restrict__ fc2b, float* __restrict__ out)
{
  const int b = blockIdx.x;
  const int j = threadIdx.x;
  __shared__ float ob[24];
  __shared__ float h[100];
  if (j < 24) ob[j] = obs[b * 24 + j];
  __syncthreads();
  if (j < 100) {
    float s = fc1b[j];
    #pragma unroll
    for (int k = 0; k < 24; k++) s = fmaf(ob[k], fc1w[j * 24 + k], s);
    h[j] = fmaxf(s, 0.f);
  }
  __syncthreads();
  if (j < 10) {
    float s = fc2b[j];
    for (int k = 0; k < 100; k++) s = fmaf(h[k], fc2w[j * 100 + k], s);
    out[128 + b * 10 + j] = fmaxf(s, 0.f);
  }
}

// ---------------------------------------------------------------------------
extern "C" void kernel_launch(void* const* d_in, const int* in_sizes, int n_in,
                              void* d_out, int out_size, void* d_ws,
                              size_t ws_size, hipStream_t stream)
{
  const float* X     = (const float*)d_in[0];
  const float* obs   = (const float*)d_in[1];
  const float* h1_w  = (const float*)d_in[2];
  const float* h1_b  = (const float*)d_in[3];
  const float* g1    = (const float*)d_in[4];
  const float* b1    = (const float*)d_in[5];
  const float* h2_w  = (const float*)d_in[6];
  const float* h2_b  = (const float*)d_in[7];
  const float* g2    = (const float*)d_in[8];
  const float* b2    = (const float*)d_in[9];
  const float* h3_w  = (const float*)d_in[10];
  const float* h3_b  = (const float*)d_in[11];
  const float* g3    = (const float*)d_in[12];
  const float* b3    = (const float*)d_in[13];
  const float* r_w   = (const float*)d_in[14];
  const float* q_w   = (const float*)d_in[15];
  const float* w_vi  = (const float*)d_in[16];
  const float* fc1_w = (const float*)d_in[17];
  const float* fc1_b = (const float*)d_in[18];
  const float* fc2_w = (const float*)d_in[19];
  const float* fc2_b = (const float*)d_in[20];
  const float* cv_w  = (const float*)d_in[21];
  const float* cv_b  = (const float*)d_in[22];
  // K (d_in[23]) fixed to 36 by setup; loop count is compile-time.

  char* ws = (char*)d_ws;
  unsigned short* t2  = (unsigned short*)ws;                       // 125,829,120 B
  unsigned short* t3  = (unsigned short*)(ws + 125829120ull);      // 109,051,904 B
  unsigned short* W2p = (unsigned short*)(ws + 234881024ull);      //     368,640 B
  unsigned short* W3p = (unsigned short*)(ws + 235249664ull);      //     294,912 B
  float*          ST  = (float*)         (ws + 235544576ull);      //       5,920 B
  float* S1 = ST +    0; float* Q1 = ST +  150; float* A1 = ST +  300; float* B1 = ST +  450;
  float* S2 = ST +  600; float* Q2 = ST +  720; float* A2 = ST +  840; float* B2 = ST +  960;
  float* S3 = ST + 1080; float* Q3 = ST + 1180; float* A3 = ST + 1280; float* B3 = ST + 1380;
  // VI buffers aliased over dead t2 region:
  float*          r   = (float*)ws;                          // 2,097,152 B
  unsigned short* qrh = (unsigned short*)(ws + 2097152ull);  // 10,485,760 B (bf16)
  float*          vA  = (float*)(ws + 12582912ull);          // 2,097,152 B
  float*          vB  = (float*)(ws + 14680064ull);          // 2,097,152 B

  hipMemsetAsync(ST, 0, 1480 * sizeof(float), stream);

  repack_w<120, 150, 160><<<720, 256, 0, stream>>>(h2_w, W2p);
  repack_w<100, 120, 128><<<576, 256, 0, stream>>>(h3_w, W3p);

  conv1_stats<<<dim3(1024, 10), 256, 0, stream>>>(X, h1_w, h1_b, S1, Q1);
  bn_finalize<150><<<1, 256, 0, stream>>>(S1, Q1, g1, b1, A1, B1);

  conv2_mfma<<<2048, 256, 0, stream>>>(X, h1_w, h1_b, A1, B1, W2p, h2_b, t2, S2, Q2);
  bn_finalize<120><<<1, 256, 0, stream>>>(S2, Q2, g2, b2, A2, B2);

  conv3_mfma<<<2048, 256, 0, stream>>>(t2, A2, B2, W3p, h3_b, t3, S3, Q3);
  bn_finalize<100><<<1, 256, 0, stream>>>(S3, Q3, g3, b3, A3, B3);

  bn3_reduce_r<<<2048, 256, 0, stream>>>(t3, A3, B3, r_w, r);

  qr_init<<<2048, 256, 0, stream>>>(r, q_w, qrh, vA);
  for (int i = 0; i < 36; i++) {
    const float* vin = (i & 1) ? vB : vA;
    float* vout      = (i & 1) ? vA : vB;
    vi_step<<<2048, 256, 0, stream>>>(vin, qrh, w_vi, vout);
  }

  float* out = (float*)d_out;
  critic_k<<<128, 256, 0, stream>>>(vA, cv_w, cv_b, out);
  action_k<<<128, 128, 0, stream>>>(obs, fc1_w, fc1_b, fc2_w, fc2_b, out);
}